// Round 5
// baseline (876.560 us; speedup 1.0000x reference)
//
#include <hip/hip_runtime.h>
#include <math.h>

#define HEAD_DIM 128
#define NH 16
#define NKV 4
#define BB 4
#define TT 2048
#define DD 2048
#define ROWS (BB*TT)   // 8192

typedef unsigned short u16;
typedef unsigned int u32;
typedef __attribute__((ext_vector_type(8))) short short8;
typedef __attribute__((ext_vector_type(4))) float f32x4;
typedef __attribute__((ext_vector_type(16))) float f32x16;
typedef __attribute__((ext_vector_type(4))) unsigned short u16x4;

__device__ __forceinline__ float bf2f(u16 u) {
    union { unsigned int i; float f; } v; v.i = ((unsigned int)u) << 16; return v.f;
}
__device__ __forceinline__ u16 f2bf(float f) {
    union { float f; unsigned int i; } v; v.f = f;
    unsigned int r = v.i + 0x7FFFu + ((v.i >> 16) & 1u);   // round-to-nearest-even
    return (u16)(r >> 16);
}
__device__ __forceinline__ f32x4 mfma16(short8 a, short8 b, f32x4 c) {
    return __builtin_amdgcn_mfma_f32_16x16x32_bf16(a, b, c, 0, 0, 0);
}
__device__ __forceinline__ f32x16 mfma32(short8 a, short8 b, f32x16 c) {
    return __builtin_amdgcn_mfma_f32_32x32x16_bf16(a, b, c, 0, 0, 0);
}
__device__ __forceinline__ f32x16 zero16() {
    f32x16 z;
    #pragma unroll
    for (int i = 0; i < 16; ++i) z[i] = 0.f;
    return z;
}

// ---------------------------------------------------------------------------
// fp32 -> bf16 cast
// ---------------------------------------------------------------------------
__global__ __launch_bounds__(256)
void cast_f2b(const float* __restrict__ in, u16* __restrict__ out, int n)
{
    int i = (blockIdx.x * 256 + threadIdx.x) * 4;
    if (i >= n) return;
    float4 v = *(const float4*)(in + i);
    u16x4 o;
    o.x = f2bf(v.x); o.y = f2bf(v.y); o.z = f2bf(v.z); o.w = f2bf(v.w);
    *(u16x4*)(out + i) = o;
}

// ---------------------------------------------------------------------------
// RoPE tables
// ---------------------------------------------------------------------------
__global__ __launch_bounds__(256)
void rope_table(float* __restrict__ cs, float* __restrict__ sn, float base)
{
    int idx = blockIdx.x * 256 + threadIdx.x;
    if (idx >= TT * 64) return;
    int t = idx >> 6;
    int d = idx & 63;
    float inv = powf(base, -(float)(2 * d) / 128.0f);
    float f = (float)t * inv;
    cs[idx] = cosf(f);
    sn[idx] = sinf(f);
}

// ---------------------------------------------------------------------------
// Fused per-head RMSNorm + rotary (+gain) with pre-scale folding, in place.
// One 64-lane wave per row of 128; lane holds pair (d, d+64).
// For Q: pre = 1/sqrt(128)*log2(e) folded so attention scores come out in
// exp2 domain with no per-score multiply.
// ---------------------------------------------------------------------------
__global__ __launch_bounds__(256)
void rmsrope_bf16(u16* __restrict__ x, const float* __restrict__ cs,
                  const float* __restrict__ sn, const float* __restrict__ gain,
                  int heads, int use_gain, float pre)
{
    int row  = blockIdx.x * 4 + (threadIdx.x >> 6);
    int lane = threadIdx.x & 63;
    int h = row % heads;
    int t = (row / heads) % TT;
    size_t base = (size_t)row * HEAD_DIM;

    float x1 = bf2f(x[base + lane]);
    float x2 = bf2f(x[base + 64 + lane]);
    float ss = x1 * x1 + x2 * x2;
    #pragma unroll
    for (int m = 1; m < 64; m <<= 1) ss += __shfl_xor(ss, m, 64);
    float r = 1.0f / sqrtf(ss * (1.0f / 128.0f) + 1.1920929e-7f);
    x1 *= r; x2 *= r;

    float c = cs[t * 64 + lane];
    float s = sn[t * 64 + lane];
    float o1 =  x1 * c + x2 * s;
    float o2 = -x1 * s + x2 * c;
    float g = use_gain ? gain[h] * pre : pre;
    o1 *= g; o2 *= g;
    x[base + lane]      = f2bf(o1);
    x[base + 64 + lane] = f2bf(o2);
}

// ---------------------------------------------------------------------------
// V transpose+relayout: vbh [B,T,KVH,128] -> vtb [B,KVH,128,T']   (bf16)
// T' = t with key-permutation: within each 32-key block, position p holds
// key with bits 2 and 3 of p swapped (self-inverse). This makes the PV
// B-fragment (P) constructible entirely in-lane from QK^T's C-layout:
// pfrag[kb*2+c][j] = p_reg[kb*16 + 8c + j].
// ---------------------------------------------------------------------------
__global__ __launch_bounds__(256)
void transpose_v(const u16* __restrict__ vbh, u16* __restrict__ vtb)
{
    __shared__ u16 tile[64][72];
    const int tb = blockIdx.x;        // t block (64)
    const int db = blockIdx.y;        // d block (64)
    const int z  = blockIdx.z;        // b*NKV + kvh
    const int tid = threadIdx.x;

    {
        const int r = tid >> 2, cq = tid & 3;
        const u16* src = vbh + ((size_t)(((z >> 2) * TT + tb * 64 + r) * NKV + (z & 3))) * 128
                             + db * 64 + cq * 16;
        short8 s0 = *(const short8*)(src);
        short8 s1 = *(const short8*)(src + 8);
        #pragma unroll
        for (int e = 0; e < 8; ++e) tile[r][cq * 16 + e]     = (u16)s0[e];
        #pragma unroll
        for (int e = 0; e < 8; ++e) tile[r][cq * 16 + 8 + e] = (u16)s1[e];
    }
    __syncthreads();
    {
        const int d = tid >> 2, tq = tid & 3;
        __attribute__((aligned(16))) u16 tmp[16];
        #pragma unroll
        for (int e = 0; e < 16; ++e) {
            int esw = (e & 3) | ((e & 4) << 1) | ((e & 8) >> 1);  // swap bits 2,3
            tmp[e] = tile[tq * 16 + esw][d];
        }
        u16* dst = vtb + ((size_t)(z * 128 + db * 64 + d)) * TT + tb * 64 + tq * 16;
        *(short8*)(dst)     = ((short8*)tmp)[0];
        *(short8*)(dst + 8) = ((short8*)tmp)[1];
    }
}

// ---------------------------------------------------------------------------
// bf16 MFMA GEMM: C[M,N] = A[M,K] @ W[N,K]^T  (unchanged)
// ---------------------------------------------------------------------------
#define LDP 40

template<int OUT_BF16>
__global__ __launch_bounds__(256)
void gemm_bf16_nt(const u16* __restrict__ A, const u16* __restrict__ W,
                  void* __restrict__ Cout, int M, int N, int K)
{
    __shared__ u16 As[128 * LDP];
    __shared__ u16 Bs[128 * LDP];
    const int tid = threadIdx.x;
    const int l = tid & 63, w = tid >> 6;
    const int lq = l & 15, lg = l >> 4;
    const int bm = blockIdx.y << 7, bn = blockIdx.x << 7;
    const int wr = (w >> 1) << 6, wc = (w & 1) << 6;

    f32x4 acc[4][4];
    #pragma unroll
    for (int m = 0; m < 4; ++m)
        #pragma unroll
        for (int n = 0; n < 4; ++n)
            acc[m][n] = (f32x4){0.f, 0.f, 0.f, 0.f};

    const int srow = tid >> 1;
    const int scol = (tid & 1) << 4;
    const u16* arow = A + (size_t)(bm + srow) * K + scol;
    const u16* brow = W + (size_t)(bn + srow) * K + scol;
    u16* asd = As + srow * LDP + scol;
    u16* bsd = Bs + srow * LDP + scol;

    for (int kt = 0; kt < K; kt += 32) {
        short8 va0 = *(const short8*)(arow + kt);
        short8 va1 = *(const short8*)(arow + kt + 8);
        short8 vb0 = *(const short8*)(brow + kt);
        short8 vb1 = *(const short8*)(brow + kt + 8);
        __syncthreads();
        *(short8*)(asd)     = va0;
        *(short8*)(asd + 8) = va1;
        *(short8*)(bsd)     = vb0;
        *(short8*)(bsd + 8) = vb1;
        __syncthreads();

        short8 af[4], bf[4];
        #pragma unroll
        for (int m = 0; m < 4; ++m)
            af[m] = *(const short8*)(As + (wr + m * 16 + lq) * LDP + lg * 8);
        #pragma unroll
        for (int n = 0; n < 4; ++n)
            bf[n] = *(const short8*)(Bs + (wc + n * 16 + lq) * LDP + lg * 8);
        #pragma unroll
        for (int m = 0; m < 4; ++m)
            #pragma unroll
            for (int n = 0; n < 4; ++n)
                acc[m][n] = mfma16(af[m], bf[n], acc[m][n]);
    }

    #pragma unroll
    for (int m = 0; m < 4; ++m) {
        int grow = bm + wr + m * 16 + lg * 4;
        #pragma unroll
        for (int n = 0; n < 4; ++n) {
            int gcol = bn + wc + n * 16 + lq;
            #pragma unroll
            for (int q = 0; q < 4; ++q) {
                if (OUT_BF16)
                    ((u16*)Cout)[(size_t)(grow + q) * N + gcol] = f2bf(acc[m][n][q]);
                else
                    ((float*)Cout)[(size_t)(grow + q) * N + gcol] = acc[m][n][q];
            }
        }
    }
}

// ---------------------------------------------------------------------------
// Causal attention, swapped-operand 32x32x16 MFMA, no LDS, no barriers.
// Each 64-lane wave owns 32 q-rows (query = lane&31). Per 64-key tile:
//   S^T = mfma(A=K, B=Q): lane holds, for ITS query, 32 of the 64 key-
//   scores (keys (r&3)+8*(r>>2)+4*hi per 32-block); softmax = in-register
//   trees + one shfl_xor(32) combine.
//   P -> bf16 B-frags PURELY IN-LANE: V^T is stored with keys permuted
//   (bits 2<->3 within each 32-block), chosen so that B-frag slot (hi,j)
//   of slice kb*2+c needs exactly register p[kb*16+8c+j]. The MFMA k-
//   enumeration cancels between A and B operands, so only relative
//   consistency matters.
//   O^T = mfma(A=V^T, B=P^T): rescale/normalize factors lane-uniform.
// Scores arrive in exp2 domain (scale*log2e folded into Q by rmsrope).
// ---------------------------------------------------------------------------
__global__ __launch_bounds__(256, 2)
void attn_mfma(const u16* __restrict__ qg, const u16* __restrict__ kg,
               const u16* __restrict__ vtg, u16* __restrict__ yg)
{
    const int h = blockIdx.y, b = blockIdx.z, kvh = h >> 2;
    const int tid = threadIdx.x;
    const int wid = tid >> 6, l = tid & 63;
    const int lq = l & 31, hi = l >> 5;
    const int hi4 = hi << 2;
    const int qsl = 63 - ((int)blockIdx.x * 4 + wid);   // heavy slots first
    const int qb = qsl * 32;
    const int qrow = qb + lq;                           // this lane's query token

    // Q fragments (B-operand): 8 k-slices of 16; lane = (query, hi-half of k)
    const u16* qptr = qg + ((size_t)((b * TT + qrow) * NH + h) << 7) + hi * 8;
    short8 qf[8];
    #pragma unroll
    for (int s = 0; s < 8; ++s)
        qf[s] = *(const short8*)(qptr + s * 16);

    f32x16 accO[4];
    #pragma unroll
    for (int db = 0; db < 4; ++db) accO[db] = zero16();
    float m2 = -1e30f, lr = 0.f;

    // K: lane covers key row (kb*32 + lq) at d-offset hi*8
    const u16* kptr = kg + ((size_t)((b * TT + lq) * NKV + kvh) << 7) + hi * 8;
    // V^T (key-permuted layout): lane covers d-row lq (+db*32) at key-pos hi*8
    const u16* vptr = vtg + ((size_t)((b * NKV + kvh) * 128 + lq)) * TT + hi * 8;

    const int ktmax = (qb + 31) >> 6;
    for (int kt = 0; kt <= ktmax; ++kt) {
        // ---- S^T = K·Q (2 key-blocks x 8 slices = 16 MFMA) ----
        const u16* kbase = kptr + (size_t)kt * (64 * NKV * 128);
        f32x16 accS0 = zero16(), accS1 = zero16();
        __builtin_amdgcn_s_setprio(1);
        #pragma unroll
        for (int s = 0; s < 8; ++s) {
            short8 kf0 = *(const short8*)(kbase + s * 16);
            accS0 = mfma32(kf0, qf[s], accS0);
        }
        #pragma unroll
        for (int s = 0; s < 8; ++s) {
            short8 kf1 = *(const short8*)(kbase + 32 * NKV * 128 + s * 16);
            accS1 = mfma32(kf1, qf[s], accS1);
        }
        __builtin_amdgcn_s_setprio(0);

        // ---- gather scores (mask on diag tile only) ----
        // p[kb*16 + r] = P[query=lq][key = kt*64 + kb*32 + (r&3)+8*(r>>2)+4*hi]
        float p[32];
        if (kt == ktmax) {
            #pragma unroll
            for (int r = 0; r < 16; ++r) {
                int key0 = kt * 64 + (r & 3) + 8 * (r >> 2) + hi4;
                p[r]      = (key0      > qrow) ? -INFINITY : accS0[r];
                p[16 + r] = (key0 + 32 > qrow) ? -INFINITY : accS1[r];
            }
        } else {
            #pragma unroll
            for (int r = 0; r < 16; ++r) { p[r] = accS0[r]; p[16 + r] = accS1[r]; }
        }

        // ---- row max (in-register tree + cross-half combine) ----
        float t16[16];
        #pragma unroll
        for (int i = 0; i < 16; ++i) t16[i] = fmaxf(p[i], p[i + 16]);
        #pragma unroll
        for (int i = 0; i < 8; ++i) t16[i] = fmaxf(t16[i], t16[i + 8]);
        #pragma unroll
        for (int i = 0; i < 4; ++i) t16[i] = fmaxf(t16[i], t16[i + 4]);
        float pm = fmaxf(fmaxf(t16[0], t16[1]), fmaxf(t16[2], t16[3]));
        pm = fmaxf(pm, __shfl_xor(pm, 32, 64));

        // ---- defer-max: skip O-rescale when max barely grew ----
        float mn = m2;
        if (!__all(pm - m2 <= 8.0f)) {
            mn = fmaxf(m2, pm);
            float al = exp2f(m2 - mn);
            lr *= al;
            #pragma unroll
            for (int db = 0; db < 4; ++db) accO[db] *= al;
            m2 = mn;
        }

        // ---- exp2 + row sum ----
        #pragma unroll
        for (int r = 0; r < 32; ++r) p[r] = exp2f(p[r] - mn);
        #pragma unroll
        for (int i = 0; i < 16; ++i) t16[i] = p[i] + p[i + 16];
        #pragma unroll
        for (int i = 0; i < 8; ++i) t16[i] += t16[i + 8];
        #pragma unroll
        for (int i = 0; i < 4; ++i) t16[i] += t16[i + 4];
        float rs = (t16[0] + t16[1]) + (t16[2] + t16[3]);
        rs += __shfl_xor(rs, 32, 64);
        lr += rs;

        // ---- P -> bf16 B-fragments, fully in-lane (V^T key-permutation) ----
        short8 pfrag[4];
        #pragma unroll
        for (int kb = 0; kb < 2; ++kb)
            #pragma unroll
            for (int c = 0; c < 2; ++c) {
                union { u16 e[8]; short8 s; } f;
                #pragma unroll
                for (int j = 0; j < 8; ++j)
                    f.e[j] = f2bf(p[kb * 16 + 8 * c + j]);
                pfrag[kb * 2 + c] = f.s;
            }

        // ---- O^T += V^T · P^T (4 d-blocks x 4 key-slices = 16 MFMA) ----
        const u16* vbase = vptr + kt * 64;
        #pragma unroll
        for (int db = 0; db < 4; ++db) {
            short8 vf0 = *(const short8*)(vbase + db * 32 * TT);
            short8 vf1 = *(const short8*)(vbase + db * 32 * TT + 16);
            short8 vf2 = *(const short8*)(vbase + db * 32 * TT + 32);
            short8 vf3 = *(const short8*)(vbase + db * 32 * TT + 48);
            __builtin_amdgcn_s_setprio(1);
            accO[db] = mfma32(vf0, pfrag[0], accO[db]);
            accO[db] = mfma32(vf1, pfrag[1], accO[db]);
            accO[db] = mfma32(vf2, pfrag[2], accO[db]);
            accO[db] = mfma32(vf3, pfrag[3], accO[db]);
            __builtin_amdgcn_s_setprio(0);
        }
    }

    // ---- epilogue: normalize (lr lane-uniform) and store ----
    float inv = 1.0f / lr;
    u16* yrow = yg + ((size_t)((b * TT + qrow) * NH + h) << 7);
    #pragma unroll
    for (int db = 0; db < 4; ++db)
        #pragma unroll
        for (int r = 0; r < 4; ++r) {
            u16x4 o;
            #pragma unroll
            for (int q = 0; q < 4; ++q) o[q] = f2bf(accO[db][4 * r + q] * inv);
            *(u16x4*)(yrow + db * 32 + 8 * r + hi4) = o;
        }
}

// ---------------------------------------------------------------------------
extern "C" void kernel_launch(void* const* d_in, const int* in_sizes, int n_in,
                              void* d_out, int out_size, void* d_ws, size_t ws_size,
                              hipStream_t stream)
{
    const float* x      = (const float*)d_in[0];
    const float* q_w    = (const float*)d_in[1];
    const float* k_w    = (const float*)d_in[2];
    const float* v_w    = (const float*)d_in[3];
    const float* out_w  = (const float*)d_in[4];
    const float* q_gain = (const float*)d_in[5];
    float* out = (float*)d_out;

    char* ws = (char*)d_ws;
    u16* qh   = (u16*)(ws);                       // 33,554,432 B
    u16* kh   = (u16*)(ws + 33554432ull);         //  8,388,608
    u16* vbh  = (u16*)(ws + 41943040ull);         //  8,388,608
    u16* vtb  = (u16*)(ws + 50331648ull);         //  8,388,608
    u16* xh   = (u16*)(ws + 58720256ull);         // 33,554,432 (xh, later y)
    u16* wbuf = (u16*)(ws + 92274688ull);         //  8,388,608 (shared weight buf)
    float* cs = (float*)(ws + 100663296ull);      //    524,288
    float* sn = cs + TT * 64;                     //    524,288

    dim3 blk(256);

    // rope tables (T=2048 > train 1024 -> NTK base scaling)
    double base = 10000.0 * pow((double)TT / 1024.0, 128.0 / 126.0);
    rope_table<<<(TT * 64) / 256, blk, 0, stream>>>(cs, sn, (float)base);

    // cast activations
    cast_f2b<<<(ROWS * DD) / 1024, blk, 0, stream>>>(x, xh, ROWS * DD);

    // projections (weight cast -> gemm, shared weight buffer)
    cast_f2b<<<(DD * DD) / 1024, blk, 0, stream>>>(q_w, wbuf, DD * DD);
    gemm_bf16_nt<1><<<dim3(DD / 128, ROWS / 128), blk, 0, stream>>>(xh, wbuf, qh, ROWS, DD, DD);
    cast_f2b<<<(512 * DD) / 1024, blk, 0, stream>>>(k_w, wbuf, 512 * DD);
    gemm_bf16_nt<1><<<dim3(512 / 128, ROWS / 128), blk, 0, stream>>>(xh, wbuf, kh, ROWS, 512, DD);
    cast_f2b<<<(512 * DD) / 1024, blk, 0, stream>>>(v_w, wbuf, 512 * DD);
    gemm_bf16_nt<1><<<dim3(512 / 128, ROWS / 128), blk, 0, stream>>>(xh, wbuf, vbh, ROWS, 512, DD);

    // fused rmsnorm + rope; Q additionally gets gain * (1/sqrt(128))*log2(e)
    const float pre_q = 0.08838834764831845f * 1.4426950408889634f;
    rmsrope_bf16<<<(ROWS * NH) / 4, blk, 0, stream>>>(qh, cs, sn, q_gain, NH, 1, pre_q);
    rmsrope_bf16<<<(ROWS * NKV) / 4, blk, 0, stream>>>(kh, cs, sn, nullptr, NKV, 0, 1.0f);

    // V -> [B,KVH,128,T] with per-32 key permutation (bits 2<->3)
    transpose_v<<<dim3(TT / 64, 2, BB * NKV), blk, 0, stream>>>(vbh, vtb);

    // attention -> y (reuses xh region; xh dead after projections)
    attn_mfma<<<dim3(16, NH, BB), blk, 0, stream>>>(qh, kh, vtb, xh);

    // output projection (fp32 out)
    cast_f2b<<<(DD * DD) / 1024, blk, 0, stream>>>(out_w, wbuf, DD * DD);
    gemm_bf16_nt<0><<<dim3(DD / 128, ROWS / 128), blk, 0, stream>>>(xh, wbuf, out, ROWS, DD, DD);
}